// Round 1
// baseline (315.653 us; speedup 1.0000x reference)
//
#include <hip/hip_runtime.h>

// TimeConcater: new_x[b,p,d] = sum_l [bucket(ts[b,l])==p] * x[b,l,d]
// B=32, L=4096, D=256, P=32 buckets over np.linspace(0,1.001,33) edges.
// Output: new_x (32,32,256) flat, then time_steps (32,4096) flat.

#define Bk 32
#define Lk 4096
#define Dk 256
#define Pk 32
#define CHUNK 512
#define NTHREADS 512

__device__ __forceinline__ int bucket_of(float tv) {
    // Emulate np.linspace(0.0, 1.001, 33): edge(i) = float32((double)i * (1.001/32))
    const double step = 1.001 / 32.0;
    int p = (int)(tv * (float)(32.0 / 1.001));
    p = p < 0 ? 0 : (p > 31 ? 31 : p);
    while (p > 0 && tv < (float)((double)p * step)) --p;
    while (p < 31 && tv >= (float)((double)(p + 1) * step)) ++p;
    return p;
}

__global__ __launch_bounds__(NTHREADS) void tc_kernel(
        const float* __restrict__ x,
        const float* __restrict__ ts,
        float* __restrict__ out) {
    __shared__ float acc[Pk * Dk];   // 32 KB bucket accumulators
    __shared__ int sbuck[CHUNK];     // per-row bucket index

    const int t = threadIdx.x;
    const int chunk = blockIdx.x;    // 0..7
    const int b = blockIdx.y;        // 0..31
    const int l0 = chunk * CHUNK;

    // Zero LDS accumulators: 8192 floats / 512 threads = 16 each.
#pragma unroll
    for (int k = 0; k < (Pk * Dk) / NTHREADS; ++k)
        acc[t + k * NTHREADS] = 0.0f;

    // One bucket per row (CHUNK == NTHREADS).
    sbuck[t] = bucket_of(ts[(size_t)b * Lk + l0 + t]);
    __syncthreads();

    // Each wave (64 lanes x float4 = 1024 B) owns one full row per iteration.
    const float* xp = x + ((size_t)b * Lk + l0) * Dk;
    const int wrow = t >> 6;           // wave id 0..7 -> row within group of 8
    const int d4 = (t & 63) << 2;      // column group, 16B aligned
    for (int i = 0; i < CHUNK / 8; ++i) {
        const int row = i * 8 + wrow;
        const float4 v = *(const float4*)(xp + (size_t)row * Dk + d4);
        const int p = sbuck[row];      // LDS broadcast (same addr per wave)
        float* a = &acc[p * Dk + d4];
        // ds_add_f32: no-return LDS atomics, no RMW dependency chain, and
        // safe against waves sharing a bucket.
        atomicAdd(&a[0], v.x);
        atomicAdd(&a[1], v.y);
        atomicAdd(&a[2], v.z);
        atomicAdd(&a[3], v.w);
    }
    __syncthreads();

    // Flush block-local bucket sums into global output (zeroed by memset node).
    float* ob = out + (size_t)b * (Pk * Dk);
#pragma unroll
    for (int k = 0; k < (Pk * Dk) / NTHREADS; ++k) {
        const int idx = t + k * NTHREADS;
        atomicAdd(&ob[idx], acc[idx]);
    }
}

extern "C" void kernel_launch(void* const* d_in, const int* in_sizes, int n_in,
                              void* d_out, int out_size, void* d_ws, size_t ws_size,
                              hipStream_t stream) {
    const float* x  = (const float*)d_in[0];
    const float* ts = (const float*)d_in[1];
    float* out = (float*)d_out;

    // Zero the new_x region (atomics accumulate onto it).
    hipMemsetAsync(out, 0, (size_t)Bk * Pk * Dk * sizeof(float), stream);
    // Passthrough copy of time_steps into the second tuple slot.
    hipMemcpyAsync(out + (size_t)Bk * Pk * Dk, ts,
                   (size_t)Bk * Lk * sizeof(float),
                   hipMemcpyDeviceToDevice, stream);

    dim3 grid(Lk / CHUNK, Bk);
    tc_kernel<<<grid, NTHREADS, 0, stream>>>(x, ts, out);
}

// Round 2
// 204.415 us; speedup vs baseline: 1.5442x; 1.5442x over previous
//
#include <hip/hip_runtime.h>

// TimeConcater: new_x[b,p,d] = sum_l [bucket(ts[b,l])==p] * x[b,l,d]
// B=32, L=4096, D=256, P=32 buckets over np.linspace(0,1.001,33) edges.
// Output flat: new_x (32,32,256), then time_steps (32,4096).
//
// R1 strategy: bucket-major gather. Phase 1 builds per-(b,bucket) compact row
// lists (counting sort, order-insensitive). Phase 2: one block per (b,bucket)
// accumulates its rows in REGISTERS (no atomics anywhere on the hot path).

#define Bk 32
#define Lk 4096
#define Dk 256
#define Pk 32

__device__ __forceinline__ int bucket_of(float tv) {
    // Emulate np.linspace(0.0, 1.001, 33): edge(i) = float32((double)i * (1.001/32))
    const double step = 1.001 / 32.0;
    int p = (int)(tv * (float)(32.0 / 1.001));
    p = p < 0 ? 0 : (p > 31 ? 31 : p);
    while (p > 0 && tv < (float)((double)p * step)) --p;
    while (p < 31 && tv >= (float)((double)(p + 1) * step)) ++p;
    return p;
}

// ---- Phase 1: per-batch counting sort of rows into buckets -----------------
// grid = B blocks x 512 threads. Also emits the ts passthrough output.
__global__ __launch_bounds__(512) void tc_bucketize(
        const float* __restrict__ ts,
        int* __restrict__ list,      // [B][L] row indices, bucket-contiguous
        int* __restrict__ bounds,    // [B][33] exclusive bucket offsets
        float* __restrict__ ts_out) {
    __shared__ int cnt[Pk];
    __shared__ int off[Pk];
    const int b = blockIdx.x;
    const int t = threadIdx.x;

    if (t < Pk) cnt[t] = 0;
    __syncthreads();

    int pv[8];
#pragma unroll
    for (int k = 0; k < 8; ++k) {
        const int l = t + k * 512;
        const float tv = ts[(size_t)b * Lk + l];
        ts_out[(size_t)b * Lk + l] = tv;          // passthrough output
        const int p = bucket_of(tv);
        pv[k] = p;
        atomicAdd(&cnt[p], 1);
    }
    __syncthreads();

    if (t == 0) {
        int s = 0;
        for (int p = 0; p < Pk; ++p) {
            off[p] = s;
            bounds[b * (Pk + 1) + p] = s;
            s += cnt[p];
        }
        bounds[b * (Pk + 1) + Pk] = s;            // == Lk
    }
    __syncthreads();

#pragma unroll
    for (int k = 0; k < 8; ++k) {
        const int l = t + k * 512;
        const int idx = atomicAdd(&off[pv[k]], 1);
        list[(size_t)b * Lk + idx] = l;
    }
}

// ---- Phase 2: register-accumulated gather ----------------------------------
// grid = (P, B) blocks x 256 threads (4 waves). Each wave covers all 256
// columns (lane -> float4 of cols) and a strided 1/4 of the bucket's rows.
__global__ __launch_bounds__(256) void tc_gather(
        const float* __restrict__ x,
        const int* __restrict__ list,
        const int* __restrict__ bounds,
        float* __restrict__ out) {
    __shared__ int rows[Lk];            // worst case: every row in one bucket
    __shared__ float red[4 * Dk];       // 4-wave partial sums

    const int p = blockIdx.x;
    const int b = blockIdx.y;
    const int t = threadIdx.x;
    const int w = t >> 6;               // wave 0..3
    const int lane = t & 63;
    const int col4 = lane << 2;         // this lane's 4 columns

    const int start = bounds[b * (Pk + 1) + p];
    const int cnt = bounds[b * (Pk + 1) + p + 1] - start;

    // Stage this bucket's row list in LDS.
    for (int i = t; i < cnt; i += 256)
        rows[i] = list[(size_t)b * Lk + start + i];
    __syncthreads();

    const float* xb = x + (size_t)b * Lk * Dk;
    float4 acc = make_float4(0.f, 0.f, 0.f, 0.f);
    for (int i = w; i < cnt; i += 4) {
        const int row = rows[i];
        const float4 v = *(const float4*)(xb + (size_t)row * Dk + col4);
        acc.x += v.x; acc.y += v.y; acc.z += v.z; acc.w += v.w;
    }

    // Reduce the 4 waves' partials.
    *(float4*)&red[t * 4] = acc;
    __syncthreads();
    if (w == 0) {
        float4 r = *(float4*)&red[lane * 4];
#pragma unroll
        for (int ww = 1; ww < 4; ++ww) {
            const float4 o = *(const float4*)&red[(ww * 64 + lane) * 4];
            r.x += o.x; r.y += o.y; r.z += o.z; r.w += o.w;
        }
        *(float4*)(out + ((size_t)b * Pk + p) * Dk + col4) = r;
    }
}

extern "C" void kernel_launch(void* const* d_in, const int* in_sizes, int n_in,
                              void* d_out, int out_size, void* d_ws, size_t ws_size,
                              hipStream_t stream) {
    const float* x  = (const float*)d_in[0];
    const float* ts = (const float*)d_in[1];
    float* out = (float*)d_out;
    float* ts_out = out + (size_t)Bk * Pk * Dk;

    int* list   = (int*)d_ws;                       // B*L ints = 512 KB
    int* bounds = list + (size_t)Bk * Lk;           // B*33 ints

    tc_bucketize<<<Bk, 512, 0, stream>>>(ts, list, bounds, ts_out);
    dim3 grid(Pk, Bk);
    tc_gather<<<grid, 256, 0, stream>>>(x, list, bounds, out);
}

// Round 3
// 203.632 us; speedup vs baseline: 1.5501x; 1.0038x over previous
//
#include <hip/hip_runtime.h>

// TimeConcater: new_x[b,p,d] = sum_l [bucket(ts[b,l])==p] * x[b,l,d]
// B=32, L=4096, D=256, P=32 buckets over np.linspace(0,1.001,33) edges.
// Output flat: new_x (32,32,256), then time_steps (32,4096).
//
// R2: single fused kernel. Each (b,p) block scans ts[b,:] itself (L2-resident,
// redundant-but-cheap), compacts matching row indices into LDS, then
// register-accumulates whole 1KB rows with a 2-deep unrolled gather stream.
// No global atomics, no inter-kernel dependency, each output written once.

#define Bk 32
#define Lk 4096
#define Dk 256
#define Pk 32

__device__ __forceinline__ int bucket_of(float tv) {
    // Emulate np.linspace(0.0, 1.001, 33): edge(i) = float32((double)i * (1.001/32))
    const double step = 1.001 / 32.0;
    int p = (int)(tv * (float)(32.0 / 1.001));
    p = p < 0 ? 0 : (p > 31 ? 31 : p);
    while (p > 0 && tv < (float)((double)p * step)) --p;
    while (p < 31 && tv >= (float)((double)(p + 1) * step)) ++p;
    return p;
}

__global__ __launch_bounds__(256) void tc_fused(
        const float* __restrict__ x,
        const float* __restrict__ ts,
        float* __restrict__ out,
        float* __restrict__ ts_out) {
    __shared__ int rows[Lk];        // 16 KB: this bucket's row indices
    __shared__ int nrows;
    __shared__ float red[4 * Dk];   // 4 KB: cross-wave reduction

    const int p = blockIdx.x;       // bucket 0..31
    const int b = blockIdx.y;       // batch 0..31
    const int t = threadIdx.x;
    const int w = t >> 6;           // wave 0..3
    const int lane = t & 63;
    const int col4 = lane << 2;     // this lane's 4 columns

    if (t == 0) nrows = 0;
    __syncthreads();

    // Scan ts[b,:] (coalesced), compact rows whose bucket == p. Block p==0
    // also emits the ts passthrough for this batch.
    const float* tsb = ts + (size_t)b * Lk;
#pragma unroll
    for (int k = 0; k < Lk / 256; ++k) {
        const int l = t + k * 256;
        const float tv = tsb[l];
        if (p == 0) ts_out[(size_t)b * Lk + l] = tv;
        if (bucket_of(tv) == p) {
            const int idx = atomicAdd(&nrows, 1);
            rows[idx] = l;
        }
    }
    __syncthreads();
    const int cnt = nrows;

    // Register gather: each wave covers all 256 cols, strided 1/4 of rows,
    // unrolled x2 for two outstanding global_load_dwordx4 per wave.
    const float* xb = x + (size_t)b * Lk * Dk;
    float4 a0 = make_float4(0.f, 0.f, 0.f, 0.f);
    float4 a1 = make_float4(0.f, 0.f, 0.f, 0.f);
    int i = w;
    for (; i + 4 < cnt; i += 8) {
        const int r0 = rows[i];
        const int r1 = rows[i + 4];
        const float4 v0 = *(const float4*)(xb + (size_t)r0 * Dk + col4);
        const float4 v1 = *(const float4*)(xb + (size_t)r1 * Dk + col4);
        a0.x += v0.x; a0.y += v0.y; a0.z += v0.z; a0.w += v0.w;
        a1.x += v1.x; a1.y += v1.y; a1.z += v1.z; a1.w += v1.w;
    }
    if (i < cnt) {
        const float4 v = *(const float4*)(xb + (size_t)rows[i] * Dk + col4);
        a0.x += v.x; a0.y += v.y; a0.z += v.z; a0.w += v.w;
    }
    a0.x += a1.x; a0.y += a1.y; a0.z += a1.z; a0.w += a1.w;

    // Reduce the 4 waves' partials; wave 0 stores the final row.
    *(float4*)&red[t * 4] = a0;
    __syncthreads();
    if (w == 0) {
        float4 r = *(float4*)&red[lane * 4];
#pragma unroll
        for (int ww = 1; ww < 4; ++ww) {
            const float4 o = *(const float4*)&red[(ww * 64 + lane) * 4];
            r.x += o.x; r.y += o.y; r.z += o.z; r.w += o.w;
        }
        *(float4*)(out + ((size_t)b * Pk + p) * Dk + col4) = r;
    }
}

extern "C" void kernel_launch(void* const* d_in, const int* in_sizes, int n_in,
                              void* d_out, int out_size, void* d_ws, size_t ws_size,
                              hipStream_t stream) {
    const float* x  = (const float*)d_in[0];
    const float* ts = (const float*)d_in[1];
    float* out = (float*)d_out;
    float* ts_out = out + (size_t)Bk * Pk * Dk;

    dim3 grid(Pk, Bk);
    tc_fused<<<grid, 256, 0, stream>>>(x, ts, out, ts_out);
}

// Round 4
// 196.944 us; speedup vs baseline: 1.6028x; 1.0340x over previous
//
#include <hip/hip_runtime.h>

// TimeConcater: new_x[b,p,d] = sum_l [bucket(ts[b,l])==p] * x[b,l,d]
// B=32, L=4096, D=256, P=32 buckets over np.linspace(0,1.001,33) edges.
// Output flat: new_x (32,32,256), then time_steps (32,4096).
//
// R3: latency-hiding push. 8 waves/block (-> 32 waves/CU), gather unrolled x4
// (4 outstanding 1KB global_load_dwordx4 per wave => 128 KB in flight/CU),
// ballot-aggregated LDS compaction (1 atomic per wave-iter).

#define Bk 32
#define Lk 4096
#define Dk 256
#define Pk 32
#define NT 512           // 8 waves
#define NW 8

__device__ __forceinline__ int bucket_of(float tv) {
    // Emulate np.linspace(0.0, 1.001, 33): edge(i) = float32((double)i * (1.001/32))
    const double step = 1.001 / 32.0;
    int p = (int)(tv * (float)(32.0 / 1.001));
    p = p < 0 ? 0 : (p > 31 ? 31 : p);
    while (p > 0 && tv < (float)((double)p * step)) --p;
    while (p < 31 && tv >= (float)((double)(p + 1) * step)) ++p;
    return p;
}

__global__ __launch_bounds__(NT, 8) void tc_fused(
        const float* __restrict__ x,
        const float* __restrict__ ts,
        float* __restrict__ out,
        float* __restrict__ ts_out) {
    __shared__ int rows[Lk];          // 16 KB worst case
    __shared__ int nrows;
    __shared__ float red[NW * Dk];    // 8 KB cross-wave reduction

    const int p = blockIdx.x;
    const int b = blockIdx.y;
    const int t = threadIdx.x;
    const int w = t >> 6;             // wave 0..7
    const int lane = t & 63;
    const int col4 = lane << 2;

    if (t == 0) nrows = 0;
    __syncthreads();

    // Scan ts[b,:]; wave-aggregated compaction of matching row indices.
    const float* tsb = ts + (size_t)b * Lk;
#pragma unroll
    for (int k = 0; k < Lk / NT; ++k) {
        const int l = t + k * NT;
        const float tv = tsb[l];
        if (p == 0) ts_out[(size_t)b * Lk + l] = tv;
        const bool match = (bucket_of(tv) == p);
        const unsigned long long m = __ballot(match);
        const int nact = __popcll(m);
        int wbase = 0;
        if (lane == 0 && nact) wbase = atomicAdd(&nrows, nact);
        wbase = __shfl(wbase, 0);
        if (match) {
            const int pre = __popcll(m & ((1ull << lane) - 1ull));
            rows[wbase + pre] = l;
        }
    }
    __syncthreads();
    const int cnt = nrows;

    // Register gather: wave w takes rows w, w+8, w+16, ...; 4 rows per
    // iteration into 4 independent accumulators (4 outstanding loads).
    const float* xb = x + (size_t)b * Lk * Dk;
    float4 a0 = make_float4(0.f, 0.f, 0.f, 0.f);
    float4 a1 = make_float4(0.f, 0.f, 0.f, 0.f);
    float4 a2 = make_float4(0.f, 0.f, 0.f, 0.f);
    float4 a3 = make_float4(0.f, 0.f, 0.f, 0.f);
    int i = w;
    for (; i + 3 * NW < cnt; i += 4 * NW) {
        const int r0 = rows[i];
        const int r1 = rows[i + NW];
        const int r2 = rows[i + 2 * NW];
        const int r3 = rows[i + 3 * NW];
        const float4 v0 = *(const float4*)(xb + (size_t)r0 * Dk + col4);
        const float4 v1 = *(const float4*)(xb + (size_t)r1 * Dk + col4);
        const float4 v2 = *(const float4*)(xb + (size_t)r2 * Dk + col4);
        const float4 v3 = *(const float4*)(xb + (size_t)r3 * Dk + col4);
        a0.x += v0.x; a0.y += v0.y; a0.z += v0.z; a0.w += v0.w;
        a1.x += v1.x; a1.y += v1.y; a1.z += v1.z; a1.w += v1.w;
        a2.x += v2.x; a2.y += v2.y; a2.z += v2.z; a2.w += v2.w;
        a3.x += v3.x; a3.y += v3.y; a3.z += v3.z; a3.w += v3.w;
    }
    for (; i < cnt; i += NW) {
        const float4 v = *(const float4*)(xb + (size_t)rows[i] * Dk + col4);
        a0.x += v.x; a0.y += v.y; a0.z += v.z; a0.w += v.w;
    }
    a0.x += a1.x; a0.y += a1.y; a0.z += a1.z; a0.w += a1.w;
    a2.x += a3.x; a2.y += a3.y; a2.z += a3.z; a2.w += a3.w;
    a0.x += a2.x; a0.y += a2.y; a0.z += a2.z; a0.w += a2.w;

    // Cross-wave reduce; wave 0 writes the final 1 KB row.
    *(float4*)&red[t * 4] = a0;
    __syncthreads();
    if (w == 0) {
        float4 r = *(float4*)&red[lane * 4];
#pragma unroll
        for (int ww = 1; ww < NW; ++ww) {
            const float4 o = *(const float4*)&red[(ww * 64 + lane) * 4];
            r.x += o.x; r.y += o.y; r.z += o.z; r.w += o.w;
        }
        *(float4*)(out + ((size_t)b * Pk + p) * Dk + col4) = r;
    }
}

extern "C" void kernel_launch(void* const* d_in, const int* in_sizes, int n_in,
                              void* d_out, int out_size, void* d_ws, size_t ws_size,
                              hipStream_t stream) {
    const float* x  = (const float*)d_in[0];
    const float* ts = (const float*)d_in[1];
    float* out = (float*)d_out;
    float* ts_out = out + (size_t)Bk * Pk * Dk;

    dim3 grid(Pk, Bk);
    tc_fused<<<grid, NT, 0, stream>>>(x, ts, out, ts_out);
}